// Round 2
// baseline (145.260 us; speedup 1.0000x reference)
//
#include <hip/hip_runtime.h>
#include <stdint.h>

#define N 4096
#define D 1024            // elements per row; fp8 => 1024 bytes per row
#define MARGIN 0.1f
#define BM 128
#define BN 128
#define BKB 128           // K-slab per tile in fp8 bytes (=128 elements)

typedef __attribute__((ext_vector_type(4))) float f32x4;
typedef __attribute__((ext_vector_type(4))) int i32x4;
typedef __attribute__((ext_vector_type(8))) int i32x8;

// Kernel 1: one wave per row (4 rows/block): fp32 norms + diagonal dot,
// butterfly shfl_xor reduce, write normalized rows as OCP fp8 e4m3
// (v_cvt_pk_fp8_f32, 4 values packed per int). Block 0 zeroes d_out.
// d_i is kept in fp32 — the only N-correlated error path stays exact.
__global__ __launch_bounds__(256) void prep_kernel(
    const float* __restrict__ W, const float* __restrict__ O,
    uint8_t* __restrict__ Wn, uint8_t* __restrict__ On,
    float* __restrict__ dvec, float* __restrict__ out) {
  const int wv = threadIdx.x >> 6, ln = threadIdx.x & 63;
  const int row = blockIdx.x * 4 + wv;
  if (blockIdx.x == 0 && threadIdx.x == 0) *out = 0.0f;
  const float4* Wr = (const float4*)(W + (size_t)row * D);
  const float4* Or = (const float4*)(O + (size_t)row * D);
  float4 w[4], o[4];
  float sw = 0.f, so = 0.f, sd = 0.f;
  #pragma unroll
  for (int c = 0; c < 4; ++c) {
    w[c] = Wr[ln + c * 64];
    o[c] = Or[ln + c * 64];
    sw += w[c].x * w[c].x + w[c].y * w[c].y + w[c].z * w[c].z + w[c].w * w[c].w;
    so += o[c].x * o[c].x + o[c].y * o[c].y + o[c].z * o[c].z + o[c].w * o[c].w;
    sd += w[c].x * o[c].x + w[c].y * o[c].y + w[c].z * o[c].z + w[c].w * o[c].w;
  }
  #pragma unroll
  for (int off = 1; off < 64; off <<= 1) {
    sw += __shfl_xor(sw, off, 64);
    so += __shfl_xor(so, off, 64);
    sd += __shfl_xor(sd, off, 64);
  }
  const float inw = 1.0f / sqrtf(sw);
  const float ino = 1.0f / sqrtf(so);
  if (ln == 0) dvec[row] = sd * inw * ino;
  int* Wo = (int*)(Wn + (size_t)row * D);
  int* Oo = (int*)(On + (size_t)row * D);
  #pragma unroll
  for (int c = 0; c < 4; ++c) {
    int pw = __builtin_amdgcn_cvt_pk_fp8_f32(w[c].x * inw, w[c].y * inw, 0, false);
    pw = __builtin_amdgcn_cvt_pk_fp8_f32(w[c].z * inw, w[c].w * inw, pw, true);
    int po = __builtin_amdgcn_cvt_pk_fp8_f32(o[c].x * ino, o[c].y * ino, 0, false);
    po = __builtin_amdgcn_cvt_pk_fp8_f32(o[c].z * ino, o[c].w * ino, po, true);
    Wo[ln + c * 64] = pw;
    Oo[ln + c * 64] = po;
  }
}

// Kernel 2: 128x128-tile MX-FP8 (K=128) MFMA GEMM + fused loss epilogue.
// R11 thesis: R10 counters showed SQ_LDS_BANK_CONFLICT = exactly 4 extra
// clk per ds_read_b64 (2x read-pipe cost). Root cause: b64 frag reads are
// processed in 16-lane phases; sub=(quad&1)*8 is constant per phase so the
// phase can only touch 16 of 32 banks -> structural 2-way conflict that NO
// 16B-granule swizzle can fix. Fix: mfma_scale_f32_16x16x128_f8f6f4 with
// scales = 1.0 (e8m0 byte 0x7F): each lane reads 32 CONTIGUOUS k-bytes =
// two ds_read_b128 of FULL granules (slots 2q^l7, (2q^l7)^1). Per phase:
// 8 slots x 4 banks x 2 lanes = exactly 2 accesses/bank = the 2-clk
// minimum -> conflict-free, staging/swizzle unchanged. Also: MFMA insts /8
// at 2.25x per-FLOP rate (MX K=128), kk-loop + its addr VALU gone, revert
// to 128^2 geometry (1024 blocks, 3 blocks/CU-class occupancy; R10's
// BM=256 = 2 blocks/CU hurt latency hiding, Occupancy 9.5%).
__global__ __launch_bounds__(256) void gemm_loss_kernel(
    const uint8_t* __restrict__ Wn, const uint8_t* __restrict__ On,
    const float* __restrict__ dvec, float* __restrict__ out) {
  __shared__ __align__(16) uint8_t ldsA[BM * BKB];  // 16 KB
  __shared__ __align__(16) uint8_t ldsB[BN * BKB];  // 16 KB
  const int bx = blockIdx.x, by = blockIdx.y;
  const int t = threadIdx.x;
  const int wv = t >> 6, ln = t & 63;
  const int wm = wv >> 1, wn = wv & 1;   // 2x2 wave grid, 64x64 per wave
  const int lrow = ln & 15;
  const int quad = ln >> 4;
  const int l7 = lrow & 7;               // == rr&7 == cc&7 for fragment rows
  // Granule pair for this lane's 32 k-bytes: global granules 2q, 2q+1.
  // Stored (swizzled) at slots (2q^l7) and (2q^l7)^1.
  const int s0 = ((quad << 1) ^ l7) << 4;

  f32x4 acc[4][4] = {};

  const uint8_t* Ag = Wn + (size_t)(by * BM) * D;
  const uint8_t* Bg = On + (size_t)(bx * BN) * D;

  for (int kt = 0; kt < D / BKB; ++kt) {           // 8 iterations
    // stage 128 rows x 128 B per tile = 1024 granules(16B); 256 thr x 4 rounds
    #pragma unroll
    for (int c = 0; c < 4; ++c) {
      const int g = c * 256 + t;         // granule index (fixed LDS slot)
      const int r = g >> 3;              // tile row (8 granules per row)
      const int gi = g & 7;              // granule slot within row
      const int col = (gi ^ (r & 7)) << 4;  // swizzled global byte col
      __builtin_amdgcn_global_load_lds(
          (const __attribute__((address_space(1))) void*)(Ag + (size_t)r * D + kt * BKB + col),
          (__attribute__((address_space(3))) void*)(ldsA + g * 16), 16, 0, 0);
      __builtin_amdgcn_global_load_lds(
          (const __attribute__((address_space(1))) void*)(Bg + (size_t)r * D + kt * BKB + col),
          (__attribute__((address_space(3))) void*)(ldsB + g * 16), 16, 0, 0);
    }
    __syncthreads();
    i32x8 aF[4], bF[4];
    #pragma unroll
    for (int mi = 0; mi < 4; ++mi) {
      const int rr = wm * 64 + mi * 16 + lrow;
      const uint8_t* p = ldsA + rr * BKB;
      i32x4 lo = *(const i32x4*)(p + s0);
      i32x4 hi = *(const i32x4*)(p + (s0 ^ 16));
      aF[mi] = __builtin_shufflevector(lo, hi, 0, 1, 2, 3, 4, 5, 6, 7);
    }
    #pragma unroll
    for (int ni = 0; ni < 4; ++ni) {
      const int cc = wn * 64 + ni * 16 + lrow;
      const uint8_t* p = ldsB + cc * BKB;
      i32x4 lo = *(const i32x4*)(p + s0);
      i32x4 hi = *(const i32x4*)(p + (s0 ^ 16));
      bF[ni] = __builtin_shufflevector(lo, hi, 0, 1, 2, 3, 4, 5, 6, 7);
    }
    #pragma unroll
    for (int mi = 0; mi < 4; ++mi)
      #pragma unroll
      for (int ni = 0; ni < 4; ++ni)
        acc[mi][ni] = __builtin_amdgcn_mfma_scale_f32_16x16x128_f8f6f4(
            aF[mi], bF[ni], acc[mi][ni],
            0, 0,                       // cbsz=fp8(e4m3), blgp=fp8(e4m3)
            0, 0x7f7f7f7f,              // scale_a opsel, bytes = 127 -> 2^0
            0, 0x7f7f7f7f);             // scale_b opsel, bytes = 127 -> 2^0
    __syncthreads();
  }

  // Epilogue: C/D layout col=lane&15, row=quad*4+reg (shape-determined,
  // dtype/FMT-independent per m127/m128; verified in-session absmax=0)
  float lsum = 0.0f;
  #pragma unroll
  for (int mi = 0; mi < 4; ++mi) {
    const int gibase = by * BM + wm * 64 + mi * 16 + quad * 4;
    #pragma unroll
    for (int r = 0; r < 4; ++r) {
      const int gi = gibase + r;
      const float di = dvec[gi];  // fp32 diagonal (accurate)
      #pragma unroll
      for (int ni = 0; ni < 4; ++ni) {
        const int gj = bx * BN + wn * 64 + ni * 16 + lrow;
        const float s = acc[mi][ni][r];
        lsum += (gi == gj) ? (1.0f - s) : fmaxf(MARGIN - s + di, 0.0f);
      }
    }
  }
  #pragma unroll
  for (int off = 32; off; off >>= 1) lsum += __shfl_down(lsum, off, 64);
  __shared__ float bsum[4];
  if (ln == 0) bsum[wv] = lsum;
  __syncthreads();
  if (t == 0) {
    const float tot = (bsum[0] + bsum[1] + bsum[2] + bsum[3]) *
                      (1.0f / ((float)N * (float)N));
    atomicAdd(out, tot);
  }
}

extern "C" void kernel_launch(void* const* d_in, const int* in_sizes, int n_in,
                              void* d_out, int out_size, void* d_ws, size_t ws_size,
                              hipStream_t stream) {
  const float* W = (const float*)d_in[0];  // wsi_embeddings (N,1,D)
  const float* O = (const float*)d_in[1];  // omic_embeddings (N,1,D)
  uint8_t* Wn = (uint8_t*)d_ws;                     // 4 MB fp8
  uint8_t* On = Wn + (size_t)N * D;                 // 4 MB fp8
  float* dvec = (float*)(On + (size_t)N * D);       // 16 KB
  float* out = (float*)d_out;

  prep_kernel<<<N / 4, 256, 0, stream>>>(W, O, Wn, On, dvec, out);
  dim3 grid(N / BN, N / BM);  // 32 x 32 = 1024 blocks
  gemm_loss_kernel<<<grid, 256, 0, stream>>>(Wn, On, dvec, out);
}